// Round 7
// baseline (167.648 us; speedup 1.0000x reference)
//
#include <hip/hip_runtime.h>
#include <hip/hip_bf16.h>
#include <stdint.h>

#define B_ 4
#define S_ 2048
#define E_ 1024
#define H_ 16
#define D_ 64
#define M_ 8192     // B*S
#define N1_ 3072    // 3*E
#define KD_ 1024
#define QSCALE 0.18033688011112042f   // 0.125 * log2(e)

typedef __attribute__((ext_vector_type(8))) short bf16x8;
typedef __attribute__((ext_vector_type(4))) float f32x4;
typedef __attribute__((ext_vector_type(16))) float f32x16;
typedef __attribute__((ext_vector_type(4))) short short4v;

__device__ __forceinline__ short f2b(float f) {
  union { float f; unsigned u; } c; c.f = f;
  unsigned u = c.u + 0x7fffu + ((c.u >> 16) & 1u);
  return (short)(u >> 16);
}

__device__ __forceinline__ float fexp2(float x) {
#if __has_builtin(__builtin_amdgcn_exp2f)
  return __builtin_amdgcn_exp2f(x);
#else
  return exp2f(x);
#endif
}

__device__ __forceinline__ unsigned cvtpk(float lo, float hi2) {
  unsigned r;
  asm("v_cvt_pk_bf16_f32 %0, %1, %2" : "=v"(r) : "v"(lo), "v"(hi2));
  return r;
}

__device__ __forceinline__ void gload16(const void* g, void* l) {
  __builtin_amdgcn_global_load_lds((const __attribute__((address_space(1))) void*)g,
                                   (__attribute__((address_space(3))) void*)l, 16, 0, 0);
}

template<int N> __device__ __forceinline__ void wait_vmcnt() {
  if constexpr (N == 0)       asm volatile("s_waitcnt vmcnt(0)" ::: "memory");
  else if constexpr (N == 3)  asm volatile("s_waitcnt vmcnt(3)" ::: "memory");
  else if constexpr (N == 4)  asm volatile("s_waitcnt vmcnt(4)" ::: "memory");
  else if constexpr (N == 6)  asm volatile("s_waitcnt vmcnt(6)" ::: "memory");
  else if constexpr (N == 8)  asm volatile("s_waitcnt vmcnt(8)" ::: "memory");
  else if constexpr (N == 9)  asm volatile("s_waitcnt vmcnt(9)" ::: "memory");
  else if constexpr (N == 12) asm volatile("s_waitcnt vmcnt(12)" ::: "memory");
  else static_assert(N == 0, "unsupported vmcnt");
}

// ---- x (f32) -> bf16, 8 elems/thread ----
__global__ void conv_kernel(const float* __restrict__ in, short* __restrict__ out) {
  int idx = blockIdx.x * 256 + threadIdx.x;
  const float4* p = (const float4*)in;
  float4 a = p[(size_t)idx * 2];
  float4 b = p[(size_t)idx * 2 + 1];
  bf16x8 v;
  v[0] = f2b(a.x); v[1] = f2b(a.y); v[2] = f2b(a.z); v[3] = f2b(a.w);
  v[4] = f2b(b.x); v[5] = f2b(b.y); v[6] = f2b(b.z); v[7] = f2b(b.w);
  *(bf16x8*)(out + (size_t)idx * 8) = v;
}

// ---- in [K][N] f32 -> out [N][K] bf16 (tiled transpose) ----
__global__ void trans_kernel(const float* __restrict__ in, short* __restrict__ out,
                             int K, int N) {
  __shared__ float tile[32][33];
  int n0 = blockIdx.x * 32, k0 = blockIdx.y * 32;
  int tx = threadIdx.x & 31, ty = threadIdx.x >> 5;
  #pragma unroll
  for (int i = 0; i < 4; ++i)
    tile[ty + i * 8][tx] = in[(size_t)(k0 + ty + i * 8) * N + n0 + tx];
  __syncthreads();
  #pragma unroll
  for (int i = 0; i < 4; ++i)
    out[(size_t)(n0 + ty + i * 8) * K + k0 + tx] = f2b(tile[tx][ty + i * 8]);
}

// ---- C = A[M][1024] * Bt[N][1024]^T + bias ; BM=MI*32, BN=NI*64, 8 waves 2x4,
//      wave tile (MI*16)x(NI*16), K-half(32) staging, 5-slot LDS ring,
//      counted vmcnt(3*LH), one raw barrier per half-phase ----
template<int MI, int NI, bool SCATTER>
__global__ __launch_bounds__(512, 2)
void gemm2(const short* __restrict__ A, const short* __restrict__ Bt,
           const float* __restrict__ bias,
           short* __restrict__ oQ, short* __restrict__ oK, short* __restrict__ oV,
           float* __restrict__ oC, int Ndim)
{
  constexpr int BM = MI * 32;            // 2 wave-rows of MI*16
  constexpr int BN = NI * 64;            // 4 wave-cols of NI*16
  constexpr int LA = BM / 128;           // A gloads / thread / half
  constexpr int LB = BN / 128;
  constexpr int LH = LA + LB;
  constexpr int HS = (BM + BN) * 64;     // bytes per half-slot
  constexpr int NH = KD_ / 32;           // 32 K-halves

  extern __shared__ char smem[];
  const int tid = threadIdx.x;
  const int l = tid & 63, w = tid >> 6;
  const int wr = w >> 2, wc = w & 3;
  const int lr = l & 15, lg = l >> 4;

  const int nwg = gridDim.x * gridDim.y;
  const int lin = blockIdx.y * gridDim.x + blockIdx.x;
  const int lin2 = (lin & 7) * (nwg >> 3) + (lin >> 3);
  const int m0 = (lin2 / gridDim.x) * BM, n0 = (lin2 % gridDim.x) * BN;

  const int srow = tid >> 2;                          // 0..127
  const int sc8 = 8 * ((tid & 3) ^ ((tid >> 3) & 3)); // pre-swizzled src col (elems)

  f32x4 acc[MI][NI] = {};

  auto stage = [&](int h) {
    char* base = smem + (h % 5) * HS;
    #pragma unroll
    for (int i = 0; i < LA; ++i)
      gload16(A + (size_t)(m0 + i * 128 + srow) * KD_ + h * 32 + sc8,
              base + i * 8192 + tid * 16);
    #pragma unroll
    for (int i = 0; i < LB; ++i)
      gload16(Bt + (size_t)(n0 + i * 128 + srow) * KD_ + h * 32 + sc8,
              base + BM * 64 + i * 8192 + tid * 16);
  };

  stage(0); stage(1); stage(2); stage(3);

  for (int h = 0; h < NH; ++h) {
    if (h <= NH - 4)      wait_vmcnt<3 * LH>();
    else if (h == NH - 3) wait_vmcnt<2 * LH>();
    else if (h == NH - 2) wait_vmcnt<LH>();
    else                  wait_vmcnt<0>();
    __builtin_amdgcn_s_barrier();
    asm volatile("" ::: "memory");
    if (h + 4 < NH) stage(h + 4);

    const char* Ac = smem + (h % 5) * HS;
    const char* Bc = Ac + BM * 64;
    bf16x8 af[MI], bfr[NI];
    #pragma unroll
    for (int mi = 0; mi < MI; ++mi) {
      const int rr = wr * (MI * 16) + mi * 16 + lr;
      af[mi] = *(const bf16x8*)(Ac + rr * 64 + ((lg ^ ((rr >> 1) & 3)) << 4));
    }
    #pragma unroll
    for (int ni = 0; ni < NI; ++ni) {
      const int rr = wc * (NI * 16) + ni * 16 + lr;
      bfr[ni] = *(const bf16x8*)(Bc + rr * 64 + ((lg ^ ((rr >> 1) & 3)) << 4));
    }
    __builtin_amdgcn_s_setprio(1);
    #pragma unroll
    for (int mi = 0; mi < MI; ++mi)
      #pragma unroll
      for (int ni = 0; ni < NI; ++ni)
        acc[mi][ni] = __builtin_amdgcn_mfma_f32_16x16x32_bf16(af[mi], bfr[ni], acc[mi][ni], 0, 0, 0);
    __builtin_amdgcn_s_setprio(0);
  }

  #pragma unroll
  for (int mi = 0; mi < MI; ++mi) {
    #pragma unroll
    for (int ni = 0; ni < NI; ++ni) {
      const int row0 = m0 + wr * (MI * 16) + mi * 16 + lg * 4;
      const int col  = n0 + wc * (NI * 16) + ni * 16 + lr;
      const float bv = bias[col];
      if constexpr (SCATTER) {
        const int which = col >> 10;
        const int e = col & 1023;
        const int h2 = e >> 6, d = e & 63;
        const int b = row0 >> 11, s = row0 & 2047;
        if (which == 2) {
          short4v pv;
          #pragma unroll
          for (int r = 0; r < 4; ++r) pv[r] = f2b(acc[mi][ni][r] + bv);
          *(short4v*)(oV + ((size_t)((b * H_ + h2) * D_ + d)) * S_ + s) = pv;
        } else {
          short* dst = which ? oK : oQ;
          const float sc = which ? 1.0f : QSCALE;
          #pragma unroll
          for (int r = 0; r < 4; ++r)
            dst[((size_t)((b * H_ + h2) * S_ + s + r)) * D_ + d] = f2b((acc[mi][ni][r] + bv) * sc);
        }
      } else {
        #pragma unroll
        for (int r = 0; r < 4; ++r)
          oC[(size_t)(row0 + r) * Ndim + col] = acc[mi][ni][r] + bv;
      }
    }
  }
}

// ---- causal flash attention (round-4 version: 1024 blocks, descending order,
//      2-way KV split, no-max softmax, stride-17 merge) ----
__global__ __launch_bounds__(512)
void attn_kernel(const short* __restrict__ Q, const short* __restrict__ K,
                 const short* __restrict__ vT, short* __restrict__ O)
{
  __shared__ short Kl[4][64 * 64];
  __shared__ short Vl[4][64 * 64];

  const int qt = (S_ / 128 - 1) - (blockIdx.x >> 6);
  const int bh = blockIdx.x & 63;
  const int tid = threadIdx.x, l = tid & 63, w = tid >> 6;
  const int qw = w & 3, g = w >> 2;
  const int lc = l & 31, hi = l >> 5;
  const int sl8 = l >> 3;
  const int scol = 8 * ((l & 7) ^ sl8);

  const short* Qb = Q  + (size_t)bh * (S_ * D_);
  const short* Kb = K  + (size_t)bh * (S_ * D_);
  const short* Vg = vT + (size_t)bh * (S_ * D_);

  const int q0w = qt * 128 + qw * 32;
  const int ktL = (q0w + 31) >> 6;
  const int NT2 = qt + 1;

  bf16x8 qr[4];
  #pragma unroll
  for (int ds = 0; ds < 4; ++ds)
    qr[ds] = *(const bf16x8*)(Qb + (size_t)(q0w + lc) * D_ + ds * 16 + hi * 8);

  f32x16 accA{}, accB{};
  float lsum = 0.f;

  auto stage = [&](int slot, int kt2) {
    short* kl = &Kl[slot][(qw * 8) * 64];
    short* vl = &Vl[slot][(qw * 8) * 64];
    const size_t kr = (size_t)(kt2 * 64 + qw * 8 + sl8);
    gload16(Kb + kr * 64 + scol, kl);
    gload16(Kb + (kr + 32) * 64 + scol, kl + 32 * 64);
    const size_t vr = (size_t)(qw * 8 + sl8);
    gload16(Vg + vr * S_ + kt2 * 64 + scol, vl);
    gload16(Vg + (vr + 32) * S_ + kt2 * 64 + scol, vl + 32 * 64);
  };

  stage(g * 2, g);
  __syncthreads();

  for (int i = 0; i < NT2; ++i) {
    const int kt = 2 * i + g;
    const int slot = g * 2 + (i & 1);
    if (i + 1 < NT2) stage(g * 2 + ((i & 1) ^ 1), kt + 2);

    if (kt <= ktL) {
      const char* Kc = (const char*)Kl[slot];
      const char* Vc = (const char*)Vl[slot];
      const int rsw = (lc & 7) << 4;
      f32x16 s0{}, s1{};
      __builtin_amdgcn_s_setprio(1);
      #pragma unroll
      for (int ds = 0; ds < 4; ++ds) {
        const int byt = ds * 32 + hi * 16;
        bf16x8 a0 = *(const bf16x8*)(Kc + lc * 128 + (byt ^ rsw));
        bf16x8 a1 = *(const bf16x8*)(Kc + (32 + lc) * 128 + (byt ^ rsw));
        s0 = __builtin_amdgcn_mfma_f32_32x32x16_bf16(a0, qr[ds], s0, 0, 0, 0);
        s1 = __builtin_amdgcn_mfma_f32_32x32x16_bf16(a1, qr[ds], s1, 0, 0, 0);
      }
      __builtin_amdgcn_s_setprio(0);
      float p[32];
      #pragma unroll
      for (int r = 0; r < 16; ++r) { p[r] = s0[r]; p[16 + r] = s1[r]; }
      if (kt == ktL) {
        const int qq = q0w + lc - kt * 64;
        #pragma unroll
        for (int r = 0; r < 16; ++r) {
          const int k0 = (r & 3) + 8 * (r >> 2) + 4 * hi;
          if (k0 > qq)      p[r]      = -1e30f;
          if (k0 + 32 > qq) p[16 + r] = -1e30f;
        }
      }
      float rs0 = 0.f, rs1 = 0.f, rs2 = 0.f, rs3 = 0.f;
      #pragma unroll
      for (int r = 0; r < 8; ++r) {
        p[r]      = fexp2(p[r]);      rs0 += p[r];
        p[8 + r]  = fexp2(p[8 + r]);  rs1 += p[8 + r];
        p[16 + r] = fexp2(p[16 + r]); rs2 += p[16 + r];
        p[24 + r] = fexp2(p[24 + r]); rs3 += p[24 + r];
      }
      float rs = (rs0 + rs1) + (rs2 + rs3);
      rs += __shfl_xor(rs, 32);
      lsum += rs;
      #pragma unroll
      for (int ks = 0; ks < 4; ++ks) {
        const int b8 = ks * 8;
        const unsigned A0 = cvtpk(p[b8 + 0], p[b8 + 1]);
        const unsigned A1 = cvtpk(p[b8 + 2], p[b8 + 3]);
        const unsigned B0 = cvtpk(p[b8 + 4], p[b8 + 5]);
        const unsigned B1 = cvtpk(p[b8 + 6], p[b8 + 7]);
        const unsigned u0 = __shfl_xor(hi ? A0 : B0, 32);
        const unsigned u1 = __shfl_xor(hi ? A1 : B1, 32);
        union { unsigned u[4]; bf16x8 v; } W;
        W.u[0] = hi ? u0 : A0;
        W.u[1] = hi ? u1 : A1;
        W.u[2] = hi ? B0 : u0;
        W.u[3] = hi ? B1 : u1;
        const int byt = ks * 32 + hi * 16;
        bf16x8 va = *(const bf16x8*)(Vc + lc * 128 + (byt ^ rsw));
        bf16x8 vb = *(const bf16x8*)(Vc + (32 + lc) * 128 + (byt ^ rsw));
        __builtin_amdgcn_s_setprio(1);
        accA = __builtin_amdgcn_mfma_f32_32x32x16_bf16(va, W.v, accA, 0, 0, 0);
        accB = __builtin_amdgcn_mfma_f32_32x32x16_bf16(vb, W.v, accB, 0, 0, 0);
        __builtin_amdgcn_s_setprio(0);
      }
    }
    __syncthreads();
  }

  float* accsA = (float*)Kl;
  float* accsB = (float*)Vl;
  float* stats = (float*)((char*)Kl + 20480);
  const int mi = qw * 64 + l;
  if (g == 1) {
    #pragma unroll
    for (int r = 0; r < 16; ++r) {
      accsA[mi * 17 + r] = accA[r];
      accsB[mi * 17 + r] = accB[r];
    }
    stats[mi] = lsum;
  }
  __syncthreads();
  if (g == 0) {
    const float rl = 1.0f / (lsum + stats[mi]);
    const int h = bh & 15, b = bh >> 4;
    short* Ob = O + ((size_t)(b * S_ + q0w + lc)) * E_ + h * 64;
    #pragma unroll
    for (int gq = 0; gq < 4; ++gq) {
      short4v o0, o1;
      #pragma unroll
      for (int i = 0; i < 4; ++i) {
        o0[i] = f2b((accA[4 * gq + i] + accsA[mi * 17 + 4 * gq + i]) * rl);
        o1[i] = f2b((accB[4 * gq + i] + accsB[mi * 17 + 4 * gq + i]) * rl);
      }
      *(short4v*)(Ob + 8 * gq + 4 * hi) = o0;
      *(short4v*)(Ob + 32 + 8 * gq + 4 * hi) = o1;
    }
  }
}

extern "C" void kernel_launch(void* const* d_in, const int* in_sizes, int n_in,
                              void* d_out, int out_size, void* d_ws, size_t ws_size,
                              hipStream_t stream)
{
  const float* x     = (const float*)d_in[0];
  const float* Wqkv  = (const float*)d_in[1];
  const float* bqkv  = (const float*)d_in[2];
  const float* Wproj = (const float*)d_in[3];
  const float* bproj = (const float*)d_in[4];
  float* out = (float*)d_out;

  char* ws = (char*)d_ws;
  short* xb     = (short*)(ws + (size_t)0);                 // 16 MB  [8192][1024]
  short* wqkvT  = (short*)(ws + (size_t)16 * 1024 * 1024);  //  6 MB  [3072][1024]
  short* wprojT = (short*)(ws + (size_t)22 * 1024 * 1024);  //  2 MB  [1024][1024]
  short* qb     = (short*)(ws + (size_t)24 * 1024 * 1024);  // 16 MB  [B][H][S][D] (scaled)
  short* kb     = (short*)(ws + (size_t)40 * 1024 * 1024);  // 16 MB  [B][H][S][D]
  short* vb     = (short*)(ws + (size_t)56 * 1024 * 1024);  // 16 MB  [B][H][D][S] (transposed)
  short* ob     = (short*)(ws + (size_t)72 * 1024 * 1024);  // 16 MB  [8192][1024]

  const int smem_qkv  = (256 + 256) * 64 * 5;   // 160 KB
  const int smem_proj = (128 + 256) * 64 * 5;   // 120 KB
  (void)hipFuncSetAttribute(reinterpret_cast<const void*>(gemm2<8, 4, true>),
                            hipFuncAttributeMaxDynamicSharedMemorySize, smem_qkv);
  (void)hipFuncSetAttribute(reinterpret_cast<const void*>(gemm2<4, 4, false>),
                            hipFuncAttributeMaxDynamicSharedMemorySize, smem_proj);

  conv_kernel<<<4096, 256, 0, stream>>>(x, xb);
  trans_kernel<<<dim3(N1_ / 32, E_ / 32), 256, 0, stream>>>(Wqkv, wqkvT, E_, N1_);
  trans_kernel<<<dim3(E_ / 32, E_ / 32), 256, 0, stream>>>(Wproj, wprojT, E_, E_);
  gemm2<8, 4, true><<<dim3(N1_ / 256, M_ / 256), 512, smem_qkv, stream>>>(
      xb, wqkvT, bqkv, qb, kb, vb, nullptr, N1_);
  attn_kernel<<<(S_ / 128) * (B_ * H_), 512, 0, stream>>>(qb, kb, vb, ob);
  gemm2<4, 4, false><<<dim3(E_ / 256, M_ / 128), 512, smem_proj, stream>>>(
      ob, wprojT, bproj, nullptr, nullptr, nullptr, out, E_);
}